// Round 15
// baseline (126.573 us; speedup 1.0000x reference)
//
#include <hip/hip_runtime.h>
#include <hip/hip_bf16.h>
#include <stdint.h>

// Problem constants
#define S_LEN 2048
#define DM    1024
#define NH    16
#define DKH   64
#define BATCH 2
#define M_ROWS (BATCH * S_LEN)   // 4096
#define NQKV   (3 * DM)          // 3072

typedef short          bf16x8v __attribute__((ext_vector_type(8)));
typedef float          f32x4   __attribute__((ext_vector_type(4)));
typedef float          f32x16  __attribute__((ext_vector_type(16)));
typedef unsigned short u16x4   __attribute__((ext_vector_type(4)));
typedef unsigned short u16x8   __attribute__((ext_vector_type(8)));
typedef unsigned int   u32x2   __attribute__((ext_vector_type(2)));
typedef unsigned int   u32x4   __attribute__((ext_vector_type(4)));

typedef const void __attribute__((address_space(1))) gas_void;
typedef void       __attribute__((address_space(3))) las_void;

static __device__ __forceinline__ unsigned short f2bf(float f) {
    union { float f; uint32_t u; } v; v.f = f;
    uint32_t u = v.u;
    uint32_t r = (u + 0x7fffu + ((u >> 16) & 1u)) >> 16;  // RNE
    return (unsigned short)r;
}

// raw v_exp_f32: D = 2^S0
static __device__ __forceinline__ float exp2_hw(float x) {
    float r;
    asm("v_exp_f32 %0, %1" : "=v"(r) : "v"(x));
    return r;
}

// pack 2 f32 -> 2 bf16 in one u32 (lo = first arg)
static __device__ __forceinline__ uint32_t cvtpk_bf16(float lo, float hi) {
    uint32_t r;
    asm("v_cvt_pk_bf16_f32 %0, %1, %2" : "=v"(r) : "v"(lo), "v"(hi));
    return r;
}
// swap: new_a = {a[0:31], b[0:31]}, new_b = {a[32:63], b[32:63]}
static __device__ __forceinline__ u32x2 pl32swap(uint32_t a, uint32_t b) {
    return __builtin_amdgcn_permlane32_swap(a, b, false, false);
}
static __device__ __forceinline__ float    fbits(uint32_t u) { return __builtin_bit_cast(float, u); }
static __device__ __forceinline__ uint32_t ubits(float f)    { return __builtin_bit_cast(uint32_t, f); }

// ---------------- fused prep: x->bf16 + W transposes (3 kernels in 1) ----------
// blocks [0,2048): cvt x; [2048,5120): transpose Wqkv; [5120,6144): transpose Wout.
__global__ __launch_bounds__(256) void prep_kernel(
    const float* __restrict__ x, unsigned short* __restrict__ xb,
    const float* __restrict__ Wqkv, unsigned short* __restrict__ wqkv_t,
    const float* __restrict__ Wout, unsigned short* __restrict__ wout_t)
{
    const int bid = blockIdx.x;
    const int tid = threadIdx.x;
    __shared__ float t[32][33];

    if (bid < 2048) {
        const int i = bid * 256 + tid;
        f32x4 a = *(const f32x4*)(x + (size_t)i * 8);
        f32x4 b = *(const f32x4*)(x + (size_t)i * 8 + 4);
        u16x8 o;
        #pragma unroll
        for (int j = 0; j < 4; ++j) { o[j] = f2bf(a[j]); o[4 + j] = f2bf(b[j]); }
        *(u16x8*)(xb + (size_t)i * 8) = o;
        return;
    }
    const float* W; unsigned short* Wt; int N, tb;
    if (bid < 2048 + 3072) { W = Wqkv; Wt = wqkv_t; N = NQKV; tb = bid - 2048; }
    else                   { W = Wout; Wt = wout_t; N = DM;   tb = bid - 5120; }
    const int K  = DM;
    const int nb = N / 32;
    const int n0 = (tb % nb) * 32, k0 = (tb / nb) * 32;
    const int tx = tid & 31, ty = tid >> 5;
    #pragma unroll
    for (int i = 0; i < 4; ++i)
        t[ty * 4 + i][tx] = W[(size_t)(k0 + ty * 4 + i) * N + n0 + tx];
    __syncthreads();
    #pragma unroll
    for (int i = 0; i < 4; ++i)
        Wt[(size_t)(n0 + ty * 4 + i) * K + k0 + tx] = f2bf(t[tx][ty * 4 + i]);
}

// ---------------- GEMM: C[M][N] = A[M][K] * Bt[N][K]^T + bias ----------------
// (R10-verbatim.) EPI==0: bf16 out; EPI==1: fp32 out.
template <int EPI>
__global__ __launch_bounds__(256) void gemm_bt_kernel(
    const unsigned short* __restrict__ A, const unsigned short* __restrict__ Bt,
    const float* __restrict__ bias, void* __restrict__ Cout,
    int M, int N, int K)
{
    __shared__ __attribute__((aligned(16))) unsigned short As[128 * 32];
    __shared__ __attribute__((aligned(16))) unsigned short Bs[128 * 32];

    const int tid  = threadIdx.x;
    const int lane = tid & 63;
    const int w    = tid >> 6;
    const int wr   = w >> 1, wc = w & 1;
    const int lr   = lane & 15, lg = lane >> 4;
    const int m0   = blockIdx.y * 128, n0 = blockIdx.x * 128;

    f32x4 acc[4][4];
    #pragma unroll
    for (int i = 0; i < 4; ++i)
        #pragma unroll
        for (int j = 0; j < 4; ++j) acc[i][j] = (f32x4){0.f, 0.f, 0.f, 0.f};

    for (int kt = 0; kt < K; kt += 32) {
        if (kt) __syncthreads();
        #pragma unroll
        for (int j = 0; j < 2; ++j) {
            const int c  = j * 256 + tid;
            const int r  = c >> 2;
            const int kc = (c & 3) * 8;
            const int cb = j * 256 + (tid & ~63);
            __builtin_amdgcn_global_load_lds(
                (gas_void*)(A + (size_t)(m0 + r) * K + kt + kc),
                (las_void*)((char*)As + (size_t)cb * 16), 16, 0, 0);
            __builtin_amdgcn_global_load_lds(
                (gas_void*)(Bt + (size_t)(n0 + r) * K + kt + kc),
                (las_void*)((char*)Bs + (size_t)cb * 16), 16, 0, 0);
        }
        __syncthreads();

        bf16x8v af[4], bfv[4];
        #pragma unroll
        for (int mi = 0; mi < 4; ++mi)
            af[mi] = *(const bf16x8v*)(&As[(wr * 64 + mi * 16 + lr) * 32 + lg * 8]);
        #pragma unroll
        for (int ni = 0; ni < 4; ++ni)
            bfv[ni] = *(const bf16x8v*)(&Bs[(wc * 64 + ni * 16 + lr) * 32 + lg * 8]);
        #pragma unroll
        for (int mi = 0; mi < 4; ++mi)
            #pragma unroll
            for (int ni = 0; ni < 4; ++ni)
                acc[mi][ni] = __builtin_amdgcn_mfma_f32_16x16x32_bf16(
                    af[mi], bfv[ni], acc[mi][ni], 0, 0, 0);
    }

    const int grow0 = m0 + wr * 64 + lg * 4;
    const int gcol0 = n0 + wc * 64 + lr;
    #pragma unroll
    for (int mi = 0; mi < 4; ++mi)
        #pragma unroll
        for (int ni = 0; ni < 4; ++ni) {
            const int gcol = gcol0 + ni * 16;
            const float bv = bias[gcol];
            #pragma unroll
            for (int r = 0; r < 4; ++r) {
                const size_t idx = (size_t)(grow0 + mi * 16 + r) * N + gcol;
                const float v = acc[mi][ni][r] + bv;
                if (EPI == 0) ((unsigned short*)Cout)[idx] = f2bf(v);
                else          ((float*)Cout)[idx] = v;
            }
        }
}

// ---------------- split V only: qkv V-block -> Vt [bh][64][s] (R10-verbatim) ----
__global__ __launch_bounds__(256) void split_v_kernel(
    const unsigned short* __restrict__ qkv, unsigned short* __restrict__ vt)
{
    const int tid = threadIdx.x;
    const int bh  = blockIdx.y;
    const int h   = bh & 15;
    const int b   = bh >> 4;
    const int s0  = blockIdx.x * 64;
    __shared__ __attribute__((aligned(16))) unsigned short tile[64][68];

    #pragma unroll
    for (int j = 0; j < 4; ++j) {
        const int c  = tid + j * 256;      // 0..1023 (chunks of 4 ushorts)
        const int r  = c >> 4;             // s row 0..63
        const int c4 = (c & 15) * 4;       // dk col 0..60
        const size_t srow = ((size_t)b * S_LEN + s0 + r) * NQKV + 2 * DM + h * 64 + c4;
        *(u16x4*)&tile[r][c4] = *(const u16x4*)(qkv + srow);
    }
    __syncthreads();
    #pragma unroll
    for (int j = 0; j < 4; ++j) {
        const int c   = tid + j * 256;
        const int dkr = c >> 4;            // dk row of Vt
        const int s4  = (c & 15) * 4;      // s col
        u16x4 o;
        #pragma unroll
        for (int i = 0; i < 4; ++i) o[i] = tile[s4 + i][dkr];
        *(u16x4*)(vt + ((size_t)bh * DKH + dkr) * S_LEN + s0 + s4) = o;
    }
}

// ---------------- flash attention: 4-wave block, LDS-staged K/V, static softmax ----
// R14 math verbatim; KVB 64 -> 128 (half the barriers/drains/stage clusters).
// K tile [128 kv][64 d] (128B rows, 8 chunks), V^T tile [64 d][128 kv] (256B rows,
// 16 chunks). Same 3-bit chunk-XOR swizzle both-sides (slot c holds global chunk
// c ^ key(row); read logical chunk g at slot g ^ key(row)). LDS 64 KB/block,
// 2 blocks/CU (128 <= 160 KB). 16 iterations x 4 sub-steps.
#define EXP_C1 0.18033688f   /* 0.125 * log2(e) : softmax temp in exp2 domain */
#define KVB 128

static __device__ __forceinline__ int swzkey(int r) { return (r ^ (r >> 3)) & 7; }

#define LDS_SUB_STEP(KsB, VsB, ks)                                                   \
do {                                                                                 \
    bf16x8v kc_[4], vc_[4];                                                          \
    _Pragma("unroll")                                                                \
    for (int s_ = 0; s_ < 4; ++s_) {                                                 \
        const int r_ = (ks) + lo;                        /* kv row 0..127 */         \
        kc_[s_] = *(const bf16x8v*)((KsB) + r_ * 128 +                               \
                                    (((s_ * 2 + hi) ^ swzkey(r_)) << 4));            \
    }                                                                                \
    _Pragma("unroll")                                                                \
    for (int j_ = 0; j_ < 4; ++j_) {                                                 \
        const int r_ = (j_ >> 1) * 32 + lo;              /* d row 0..63 */           \
        const int cc_ = ((ks) >> 3) + (j_ & 1) * 2 + hi; /* kv chunk 0..15 */        \
        vc_[j_] = *(const bf16x8v*)((VsB) + r_ * 256 +                               \
                                    ((cc_ ^ swzkey(r_)) << 4));                      \
    }                                                                                \
    f32x16 scA = {}, scB = {};                                                       \
    __builtin_amdgcn_s_setprio(1);                                                   \
    scA = __builtin_amdgcn_mfma_f32_32x32x16_bf16(kc_[0], qf[0], scA, 0, 0, 0);      \
    scB = __builtin_amdgcn_mfma_f32_32x32x16_bf16(kc_[1], qf[1], scB, 0, 0, 0);      \
    scA = __builtin_amdgcn_mfma_f32_32x32x16_bf16(kc_[2], qf[2], scA, 0, 0, 0);      \
    scB = __builtin_amdgcn_mfma_f32_32x32x16_bf16(kc_[3], qf[3], scB, 0, 0, 0);      \
    __builtin_amdgcn_s_setprio(0);                                                   \
    f32x16 sc = scA + scB;                                                           \
    float pe_[16];                                                                   \
    _Pragma("unroll")                                                                \
    for (int r_ = 0; r_ < 16; ++r_)                                                  \
        pe_[r_] = exp2_hw(sc[r_] * EXP_C1);                                          \
    float u0_ = (pe_[0] + pe_[1]) + (pe_[2] + pe_[3]);                               \
    float u1_ = (pe_[4] + pe_[5]) + (pe_[6] + pe_[7]);                               \
    float u2_ = (pe_[8] + pe_[9]) + (pe_[10] + pe_[11]);                             \
    float u3_ = (pe_[12] + pe_[13]) + (pe_[14] + pe_[15]);                           \
    float ss_ = (u0_ + u1_) + (u2_ + u3_);                                           \
    { u32x2 sw_ = pl32swap(ubits(ss_), ubits(ss_));                                  \
      ss_ = fbits(sw_[0]) + fbits(sw_[1]); }                                         \
    lsum += ss_;                                                                     \
    uint32_t a01_ = cvtpk_bf16(pe_[0],  pe_[1]),  a23_ = cvtpk_bf16(pe_[2],  pe_[3]);  \
    uint32_t a45_ = cvtpk_bf16(pe_[4],  pe_[5]),  a67_ = cvtpk_bf16(pe_[6],  pe_[7]);  \
    uint32_t b01_ = cvtpk_bf16(pe_[8],  pe_[9]),  b23_ = cvtpk_bf16(pe_[10], pe_[11]); \
    uint32_t b45_ = cvtpk_bf16(pe_[12], pe_[13]), b67_ = cvtpk_bf16(pe_[14], pe_[15]); \
    u32x2 s0_ = pl32swap(a01_, a45_);                                                \
    u32x2 s1_ = pl32swap(a23_, a67_);                                                \
    u32x2 s2_ = pl32swap(b01_, b45_);                                                \
    u32x2 s3_ = pl32swap(b23_, b67_);                                                \
    u32x4 w0_ = { s0_[0], s1_[0], s0_[1], s1_[1] };                                  \
    u32x4 w1_ = { s2_[0], s3_[0], s2_[1], s3_[1] };                                  \
    bf16x8v pa0_ = __builtin_bit_cast(bf16x8v, w0_);                                 \
    bf16x8v pa1_ = __builtin_bit_cast(bf16x8v, w1_);                                 \
    __builtin_amdgcn_s_setprio(1);                                                   \
    acc0 = __builtin_amdgcn_mfma_f32_32x32x16_bf16(vc_[0], pa0_, acc0, 0, 0, 0);     \
    acc0 = __builtin_amdgcn_mfma_f32_32x32x16_bf16(vc_[1], pa1_, acc0, 0, 0, 0);     \
    acc1 = __builtin_amdgcn_mfma_f32_32x32x16_bf16(vc_[2], pa0_, acc1, 0, 0, 0);     \
    acc1 = __builtin_amdgcn_mfma_f32_32x32x16_bf16(vc_[3], pa1_, acc1, 0, 0, 0);     \
    __builtin_amdgcn_s_setprio(0);                                                   \
} while (0)

__global__ __launch_bounds__(256, 2) void attn_kernel(
    const unsigned short* __restrict__ QKV, const unsigned short* __restrict__ Vt,
    unsigned short* __restrict__ O)
{
    const int tid  = threadIdx.x;
    const int w    = tid >> 6;
    const int lane = tid & 63;
    const int lo = lane & 31;
    const int hi = lane >> 5;

    // T1: XCD-chunked bijective swizzle; 512 blocks = 8 XCDs x 64.
    const int flat = blockIdx.x;
    const int virt = (flat & 7) * 64 + (flat >> 3);
    const int bh = virt >> 4;          // 0..31
    const int qb = virt & 15;          // 0..15
    const int b = bh >> 4, h = bh & 15;
    const int q0 = qb * 128 + w * 32;

    // K tile [128][64] (16 KB) + V^T tile [64][128] (16 KB), dbuf -> 64 KB.
    __shared__ __attribute__((aligned(16))) unsigned short Ks[2][KVB * 64];
    __shared__ __attribute__((aligned(16))) unsigned short Vs[2][64 * KVB];

    const unsigned short* Kq  = QKV + (size_t)b * S_LEN * NQKV + DM + h * 64;
    const unsigned short* Vtb = Vt + (size_t)bh * DKH * S_LEN;   // [64][2048]

    // --- staging maps (256 threads, 4 issues per operand per tile) ---
    // K: chunk = j*256 + tid; row = chunk>>3 (kv 0..127), slot = tid&7.
    const int ksr = tid >> 3, kcn = tid & 7;
    size_t kSrc[4];
    #pragma unroll
    for (int j = 0; j < 4; ++j) {
        const int r = j * 32 + ksr;
        kSrc[j] = (size_t)r * NQKV + ((kcn ^ swzkey(r)) * 8);
    }
    // V: chunk = j*256 + tid; row = chunk>>4 (d 0..63), slot = tid&15.
    const int vsr = tid >> 4, vcn = tid & 15;
    size_t vSrc[4];
    #pragma unroll
    for (int j = 0; j < 4; ++j) {
        const int r = j * 16 + vsr;
        vSrc[j] = (size_t)r * S_LEN + ((vcn ^ swzkey(r)) * 8);
    }
    const int dstBase = (tid & ~63) * 16;  // + j*4096 per issue

#define STAGE_TILE(buf, kvOff)                                                        \
    do {                                                                              \
        _Pragma("unroll")                                                             \
        for (int j = 0; j < 4; ++j)                                                   \
            __builtin_amdgcn_global_load_lds(                                         \
                (gas_void*)(Kq + (size_t)(kvOff) * NQKV + kSrc[j]),                   \
                (las_void*)((char*)&Ks[buf][0] + dstBase + j * 4096), 16, 0, 0);      \
        _Pragma("unroll")                                                             \
        for (int j = 0; j < 4; ++j)                                                   \
            __builtin_amdgcn_global_load_lds(                                         \
                (gas_void*)(Vtb + (kvOff) + vSrc[j]),                                 \
                (las_void*)((char*)&Vs[buf][0] + dstBase + j * 4096), 16, 0, 0);      \
    } while (0)

    const unsigned short* Qp =
        QKV + ((size_t)b * S_LEN + q0 + lo) * NQKV + h * 64 + hi * 8;
    bf16x8v qf[4];
    #pragma unroll
    for (int s = 0; s < 4; ++s) qf[s] = *(const bf16x8v*)(Qp + s * 16);

    f32x16 acc0 = {}, acc1 = {};
    float lsum = 0.f;

    STAGE_TILE(0, 0);
    __syncthreads();

    int cur = 0;
    for (int t = 0; t < S_LEN / KVB; ++t) {   // 16 iterations
        const int nxt = cur ^ 1;
        if (t + 1 < S_LEN / KVB) STAGE_TILE(nxt, (t + 1) * KVB);
        const char* KsB = (const char*)&Ks[cur][0];
        const char* VsB = (const char*)&Vs[cur][0];
        LDS_SUB_STEP(KsB, VsB, 0);
        LDS_SUB_STEP(KsB, VsB, 32);
        LDS_SUB_STEP(KsB, VsB, 64);
        LDS_SUB_STEP(KsB, VsB, 96);
        __syncthreads();
        cur = nxt;
    }
#undef STAGE_TILE

    const float linv = 1.f / lsum;
    unsigned short* Orow = O + ((size_t)b * S_LEN + q0 + lo) * DM + h * 64 + hi * 4;
    #pragma unroll
    for (int g = 0; g < 4; ++g) {
        u16x4 st0, st1;
        #pragma unroll
        for (int k2 = 0; k2 < 4; ++k2) {
            st0[k2] = f2bf(acc0[g * 4 + k2] * linv);
            st1[k2] = f2bf(acc1[g * 4 + k2] * linv);
        }
        *(u16x4*)(Orow + g * 8)      = st0;
        *(u16x4*)(Orow + 32 + g * 8) = st1;
    }
}

// ---------------- host launcher ----------------
extern "C" void kernel_launch(void* const* d_in, const int* in_sizes, int n_in,
                              void* d_out, int out_size, void* d_ws, size_t ws_size,
                              hipStream_t stream)
{
    const float* x    = (const float*)d_in[0];
    const float* Wqkv = (const float*)d_in[1];
    const float* bqkv = (const float*)d_in[2];
    const float* Wout = (const float*)d_in[3];
    const float* bout = (const float*)d_in[4];
    float* out = (float*)d_out;

    char* ws = (char*)d_ws;
    // layout (bytes):
    //  [0,         8388608)  xb (x bf16; dead after QKV GEMM)
    //  [8388608,  14680064)  wqkv_t bf16 [3072][1024]
    //  [14680064, 16777216)  wout_t bf16 [1024][1024]
    //  [16777216, 41943040)  qkvb bf16 [4096][3072]  (LIVE through attn: Q,K read from it)
    //  [41943040, 50331648)  attn_o bf16 [4096][1024]
    //  [50331648, 58720256)  vtb bf16 [32][64][2048]
    unsigned short* xb     = (unsigned short*)(ws);
    unsigned short* wqkv_t = (unsigned short*)(ws + 8388608);
    unsigned short* wout_t = (unsigned short*)(ws + 14680064);
    unsigned short* qkvb   = (unsigned short*)(ws + 16777216);
    unsigned short* attn_o = (unsigned short*)(ws + 41943040);
    unsigned short* vtb    = (unsigned short*)(ws + 50331648);

    prep_kernel<<<6144, 256, 0, stream>>>(x, xb, Wqkv, wqkv_t, Wout, wout_t);
    gemm_bt_kernel<0><<<dim3(NQKV / 128, M_ROWS / 128), 256, 0, stream>>>(
        xb, wqkv_t, bqkv, (void*)qkvb, M_ROWS, NQKV, DM);
    split_v_kernel<<<dim3(S_LEN / 64, BATCH * NH), 256, 0, stream>>>(qkvb, vtb);
    attn_kernel<<<512, 256, 0, stream>>>(qkvb, vtb, attn_o);
    gemm_bt_kernel<1><<<dim3(DM / 128, M_ROWS / 128), 256, 0, stream>>>(
        attn_o, wout_t, bout, (void*)out, M_ROWS, DM, DM);
}

// Round 16
// 125.324 us; speedup vs baseline: 1.0100x; 1.0100x over previous
//
#include <hip/hip_runtime.h>
#include <hip/hip_bf16.h>
#include <stdint.h>

// Problem constants
#define S_LEN 2048
#define DM    1024
#define NH    16
#define DKH   64
#define BATCH 2
#define M_ROWS (BATCH * S_LEN)   // 4096
#define NQKV   (3 * DM)          // 3072

typedef short          bf16x8v __attribute__((ext_vector_type(8)));
typedef float          f32x4   __attribute__((ext_vector_type(4)));
typedef float          f32x16  __attribute__((ext_vector_type(16)));
typedef unsigned short u16x4   __attribute__((ext_vector_type(4)));
typedef unsigned short u16x8   __attribute__((ext_vector_type(8)));
typedef unsigned int   u32x2   __attribute__((ext_vector_type(2)));
typedef unsigned int   u32x4   __attribute__((ext_vector_type(4)));

typedef const void __attribute__((address_space(1))) gas_void;
typedef void       __attribute__((address_space(3))) las_void;

static __device__ __forceinline__ unsigned short f2bf(float f) {
    union { float f; uint32_t u; } v; v.f = f;
    uint32_t u = v.u;
    uint32_t r = (u + 0x7fffu + ((u >> 16) & 1u)) >> 16;  // RNE
    return (unsigned short)r;
}

// raw v_exp_f32: D = 2^S0
static __device__ __forceinline__ float exp2_hw(float x) {
    float r;
    asm("v_exp_f32 %0, %1" : "=v"(r) : "v"(x));
    return r;
}

// pack 2 f32 -> 2 bf16 in one u32 (lo = first arg)
static __device__ __forceinline__ uint32_t cvtpk_bf16(float lo, float hi) {
    uint32_t r;
    asm("v_cvt_pk_bf16_f32 %0, %1, %2" : "=v"(r) : "v"(lo), "v"(hi));
    return r;
}
// swap: new_a = {a[0:31], b[0:31]}, new_b = {a[32:63], b[32:63]}
static __device__ __forceinline__ u32x2 pl32swap(uint32_t a, uint32_t b) {
    return __builtin_amdgcn_permlane32_swap(a, b, false, false);
}
static __device__ __forceinline__ float    fbits(uint32_t u) { return __builtin_bit_cast(float, u); }
static __device__ __forceinline__ uint32_t ubits(float f)    { return __builtin_bit_cast(uint32_t, f); }

// ---------------- fused prep: x->bf16 + W transposes (3 kernels in 1) ----------
// blocks [0,2048): cvt x; [2048,5120): transpose Wqkv; [5120,6144): transpose Wout.
__global__ __launch_bounds__(256) void prep_kernel(
    const float* __restrict__ x, unsigned short* __restrict__ xb,
    const float* __restrict__ Wqkv, unsigned short* __restrict__ wqkv_t,
    const float* __restrict__ Wout, unsigned short* __restrict__ wout_t)
{
    const int bid = blockIdx.x;
    const int tid = threadIdx.x;
    __shared__ float t[32][33];

    if (bid < 2048) {
        const int i = bid * 256 + tid;
        f32x4 a = *(const f32x4*)(x + (size_t)i * 8);
        f32x4 b = *(const f32x4*)(x + (size_t)i * 8 + 4);
        u16x8 o;
        #pragma unroll
        for (int j = 0; j < 4; ++j) { o[j] = f2bf(a[j]); o[4 + j] = f2bf(b[j]); }
        *(u16x8*)(xb + (size_t)i * 8) = o;
        return;
    }
    const float* W; unsigned short* Wt; int N, tb;
    if (bid < 2048 + 3072) { W = Wqkv; Wt = wqkv_t; N = NQKV; tb = bid - 2048; }
    else                   { W = Wout; Wt = wout_t; N = DM;   tb = bid - 5120; }
    const int K  = DM;
    const int nb = N / 32;
    const int n0 = (tb % nb) * 32, k0 = (tb / nb) * 32;
    const int tx = tid & 31, ty = tid >> 5;
    #pragma unroll
    for (int i = 0; i < 4; ++i)
        t[ty * 4 + i][tx] = W[(size_t)(k0 + ty * 4 + i) * N + n0 + tx];
    __syncthreads();
    #pragma unroll
    for (int i = 0; i < 4; ++i)
        Wt[(size_t)(n0 + ty * 4 + i) * K + k0 + tx] = f2bf(t[tx][ty * 4 + i]);
}

// ---------------- GEMM: C[M][N] = A[M][K] * Bt[N][K]^T + bias ----------------
// (R10-verbatim.) EPI==0: bf16 out; EPI==1: fp32 out.
template <int EPI>
__global__ __launch_bounds__(256) void gemm_bt_kernel(
    const unsigned short* __restrict__ A, const unsigned short* __restrict__ Bt,
    const float* __restrict__ bias, void* __restrict__ Cout,
    int M, int N, int K)
{
    __shared__ __attribute__((aligned(16))) unsigned short As[128 * 32];
    __shared__ __attribute__((aligned(16))) unsigned short Bs[128 * 32];

    const int tid  = threadIdx.x;
    const int lane = tid & 63;
    const int w    = tid >> 6;
    const int wr   = w >> 1, wc = w & 1;
    const int lr   = lane & 15, lg = lane >> 4;
    const int m0   = blockIdx.y * 128, n0 = blockIdx.x * 128;

    f32x4 acc[4][4];
    #pragma unroll
    for (int i = 0; i < 4; ++i)
        #pragma unroll
        for (int j = 0; j < 4; ++j) acc[i][j] = (f32x4){0.f, 0.f, 0.f, 0.f};

    for (int kt = 0; kt < K; kt += 32) {
        if (kt) __syncthreads();
        #pragma unroll
        for (int j = 0; j < 2; ++j) {
            const int c  = j * 256 + tid;
            const int r  = c >> 2;
            const int kc = (c & 3) * 8;
            const int cb = j * 256 + (tid & ~63);
            __builtin_amdgcn_global_load_lds(
                (gas_void*)(A + (size_t)(m0 + r) * K + kt + kc),
                (las_void*)((char*)As + (size_t)cb * 16), 16, 0, 0);
            __builtin_amdgcn_global_load_lds(
                (gas_void*)(Bt + (size_t)(n0 + r) * K + kt + kc),
                (las_void*)((char*)Bs + (size_t)cb * 16), 16, 0, 0);
        }
        __syncthreads();

        bf16x8v af[4], bfv[4];
        #pragma unroll
        for (int mi = 0; mi < 4; ++mi)
            af[mi] = *(const bf16x8v*)(&As[(wr * 64 + mi * 16 + lr) * 32 + lg * 8]);
        #pragma unroll
        for (int ni = 0; ni < 4; ++ni)
            bfv[ni] = *(const bf16x8v*)(&Bs[(wc * 64 + ni * 16 + lr) * 32 + lg * 8]);
        #pragma unroll
        for (int mi = 0; mi < 4; ++mi)
            #pragma unroll
            for (int ni = 0; ni < 4; ++ni)
                acc[mi][ni] = __builtin_amdgcn_mfma_f32_16x16x32_bf16(
                    af[mi], bfv[ni], acc[mi][ni], 0, 0, 0);
    }

    const int grow0 = m0 + wr * 64 + lg * 4;
    const int gcol0 = n0 + wc * 64 + lr;
    #pragma unroll
    for (int mi = 0; mi < 4; ++mi)
        #pragma unroll
        for (int ni = 0; ni < 4; ++ni) {
            const int gcol = gcol0 + ni * 16;
            const float bv = bias[gcol];
            #pragma unroll
            for (int r = 0; r < 4; ++r) {
                const size_t idx = (size_t)(grow0 + mi * 16 + r) * N + gcol;
                const float v = acc[mi][ni][r] + bv;
                if (EPI == 0) ((unsigned short*)Cout)[idx] = f2bf(v);
                else          ((float*)Cout)[idx] = v;
            }
        }
}

// ---------------- split V only: qkv V-block -> Vt [bh][64][s] (R10-verbatim) ----
__global__ __launch_bounds__(256) void split_v_kernel(
    const unsigned short* __restrict__ qkv, unsigned short* __restrict__ vt)
{
    const int tid = threadIdx.x;
    const int bh  = blockIdx.y;
    const int h   = bh & 15;
    const int b   = bh >> 4;
    const int s0  = blockIdx.x * 64;
    __shared__ __attribute__((aligned(16))) unsigned short tile[64][68];

    #pragma unroll
    for (int j = 0; j < 4; ++j) {
        const int c  = tid + j * 256;      // 0..1023 (chunks of 4 ushorts)
        const int r  = c >> 4;             // s row 0..63
        const int c4 = (c & 15) * 4;       // dk col 0..60
        const size_t srow = ((size_t)b * S_LEN + s0 + r) * NQKV + 2 * DM + h * 64 + c4;
        *(u16x4*)&tile[r][c4] = *(const u16x4*)(qkv + srow);
    }
    __syncthreads();
    #pragma unroll
    for (int j = 0; j < 4; ++j) {
        const int c   = tid + j * 256;
        const int dkr = c >> 4;            // dk row of Vt
        const int s4  = (c & 15) * 4;      // s col
        u16x4 o;
        #pragma unroll
        for (int i = 0; i < 4; ++i) o[i] = tile[s4 + i][dkr];
        *(u16x4*)(vt + ((size_t)bh * DKH + dkr) * S_LEN + s0 + s4) = o;
    }
}

// ---------------- flash attention: 4-wave block, LDS-staged K/V, static softmax ----
// (R10/R14 kernel, verbatim — best measured config: 58 µs.)
#define EXP_C1 0.18033688f   /* 0.125 * log2(e) : softmax temp in exp2 domain */
#define KVB 64

static __device__ __forceinline__ int swzkey(int r) { return (r ^ (r >> 3)) & 7; }

#define LDS_SUB_STEP(KsB, VsB, ks)                                                   \
do {                                                                                 \
    bf16x8v kc_[4], vc_[4];                                                          \
    _Pragma("unroll")                                                                \
    for (int s_ = 0; s_ < 4; ++s_) {                                                 \
        const int r_ = (ks) + lo;                                                    \
        kc_[s_] = *(const bf16x8v*)((KsB) + r_ * 128 +                               \
                                    (((s_ * 2 + hi) ^ swzkey(r_)) << 4));            \
    }                                                                                \
    _Pragma("unroll")                                                                \
    for (int j_ = 0; j_ < 4; ++j_) {                                                 \
        const int r_ = (j_ >> 1) * 32 + lo;                                          \
        const int cc_ = ((ks) >> 3) + (j_ & 1) * 2 + hi;                             \
        vc_[j_] = *(const bf16x8v*)((VsB) + r_ * 128 +                               \
                                    ((cc_ ^ swzkey(r_)) << 4));                      \
    }                                                                                \
    f32x16 scA = {}, scB = {};                                                       \
    __builtin_amdgcn_s_setprio(1);                                                   \
    scA = __builtin_amdgcn_mfma_f32_32x32x16_bf16(kc_[0], qf[0], scA, 0, 0, 0);      \
    scB = __builtin_amdgcn_mfma_f32_32x32x16_bf16(kc_[1], qf[1], scB, 0, 0, 0);      \
    scA = __builtin_amdgcn_mfma_f32_32x32x16_bf16(kc_[2], qf[2], scA, 0, 0, 0);      \
    scB = __builtin_amdgcn_mfma_f32_32x32x16_bf16(kc_[3], qf[3], scB, 0, 0, 0);      \
    __builtin_amdgcn_s_setprio(0);                                                   \
    f32x16 sc = scA + scB;                                                           \
    float pe_[16];                                                                   \
    _Pragma("unroll")                                                                \
    for (int r_ = 0; r_ < 16; ++r_)                                                  \
        pe_[r_] = exp2_hw(sc[r_] * EXP_C1);                                          \
    float u0_ = (pe_[0] + pe_[1]) + (pe_[2] + pe_[3]);                               \
    float u1_ = (pe_[4] + pe_[5]) + (pe_[6] + pe_[7]);                               \
    float u2_ = (pe_[8] + pe_[9]) + (pe_[10] + pe_[11]);                             \
    float u3_ = (pe_[12] + pe_[13]) + (pe_[14] + pe_[15]);                           \
    float ss_ = (u0_ + u1_) + (u2_ + u3_);                                           \
    { u32x2 sw_ = pl32swap(ubits(ss_), ubits(ss_));                                  \
      ss_ = fbits(sw_[0]) + fbits(sw_[1]); }                                         \
    lsum += ss_;                                                                     \
    uint32_t a01_ = cvtpk_bf16(pe_[0],  pe_[1]),  a23_ = cvtpk_bf16(pe_[2],  pe_[3]);  \
    uint32_t a45_ = cvtpk_bf16(pe_[4],  pe_[5]),  a67_ = cvtpk_bf16(pe_[6],  pe_[7]);  \
    uint32_t b01_ = cvtpk_bf16(pe_[8],  pe_[9]),  b23_ = cvtpk_bf16(pe_[10], pe_[11]); \
    uint32_t b45_ = cvtpk_bf16(pe_[12], pe_[13]), b67_ = cvtpk_bf16(pe_[14], pe_[15]); \
    u32x2 s0_ = pl32swap(a01_, a45_);                                                \
    u32x2 s1_ = pl32swap(a23_, a67_);                                                \
    u32x2 s2_ = pl32swap(b01_, b45_);                                                \
    u32x2 s3_ = pl32swap(b23_, b67_);                                                \
    u32x4 w0_ = { s0_[0], s1_[0], s0_[1], s1_[1] };                                  \
    u32x4 w1_ = { s2_[0], s3_[0], s2_[1], s3_[1] };                                  \
    bf16x8v pa0_ = __builtin_bit_cast(bf16x8v, w0_);                                 \
    bf16x8v pa1_ = __builtin_bit_cast(bf16x8v, w1_);                                 \
    __builtin_amdgcn_s_setprio(1);                                                   \
    acc0 = __builtin_amdgcn_mfma_f32_32x32x16_bf16(vc_[0], pa0_, acc0, 0, 0, 0);     \
    acc0 = __builtin_amdgcn_mfma_f32_32x32x16_bf16(vc_[1], pa1_, acc0, 0, 0, 0);     \
    acc1 = __builtin_amdgcn_mfma_f32_32x32x16_bf16(vc_[2], pa0_, acc1, 0, 0, 0);     \
    acc1 = __builtin_amdgcn_mfma_f32_32x32x16_bf16(vc_[3], pa1_, acc1, 0, 0, 0);     \
    __builtin_amdgcn_s_setprio(0);                                                   \
} while (0)

__global__ __launch_bounds__(256, 2) void attn_kernel(
    const unsigned short* __restrict__ QKV, const unsigned short* __restrict__ Vt,
    unsigned short* __restrict__ O)
{
    const int tid  = threadIdx.x;
    const int w    = tid >> 6;
    const int lane = tid & 63;
    const int lo = lane & 31;
    const int hi = lane >> 5;

    // T1: XCD-chunked bijective swizzle; 512 blocks = 8 XCDs x 64.
    const int flat = blockIdx.x;
    const int virt = (flat & 7) * 64 + (flat >> 3);
    const int bh = virt >> 4;          // 0..31
    const int qb = virt & 15;          // 0..15
    const int b = bh >> 4, h = bh & 15;
    const int q0 = qb * 128 + w * 32;

    __shared__ __attribute__((aligned(16))) unsigned short Ks[2][KVB * 64];
    __shared__ __attribute__((aligned(16))) unsigned short Vs[2][KVB * 64];

    const unsigned short* Kq  = QKV + (size_t)b * S_LEN * NQKV + DM + h * 64;
    const unsigned short* Vtb = Vt + (size_t)bh * DKH * S_LEN;   // [64][2048]

    const int sr  = tid >> 3, scn = tid & 7;
    const size_t kSrc0 = (size_t)sr * NQKV + ((scn ^ swzkey(sr)) * 8);
    const size_t kSrc1 = (size_t)(sr + 32) * NQKV + ((scn ^ swzkey(sr + 32)) * 8);
    const size_t vSrc0 = (size_t)sr * S_LEN + ((scn ^ swzkey(sr)) * 8);
    const size_t vSrc1 = (size_t)(sr + 32) * S_LEN + ((scn ^ swzkey(sr + 32)) * 8);
    const int dstOff0 = (tid & ~63) * 16;
    const int dstOff1 = dstOff0 + 4096;

#define STAGE_TILE(buf, kvOff)                                                        \
    do {                                                                              \
        __builtin_amdgcn_global_load_lds((gas_void*)(Kq + (kvOff) * NQKV + kSrc0),    \
            (las_void*)((char*)&Ks[buf][0] + dstOff0), 16, 0, 0);                     \
        __builtin_amdgcn_global_load_lds((gas_void*)(Kq + (kvOff) * NQKV + kSrc1),    \
            (las_void*)((char*)&Ks[buf][0] + dstOff1), 16, 0, 0);                     \
        __builtin_amdgcn_global_load_lds((gas_void*)(Vtb + (kvOff) + vSrc0),          \
            (las_void*)((char*)&Vs[buf][0] + dstOff0), 16, 0, 0);                     \
        __builtin_amdgcn_global_load_lds((gas_void*)(Vtb + (kvOff) + vSrc1),          \
            (las_void*)((char*)&Vs[buf][0] + dstOff1), 16, 0, 0);                     \
    } while (0)

    const unsigned short* Qp =
        QKV + ((size_t)b * S_LEN + q0 + lo) * NQKV + h * 64 + hi * 8;
    bf16x8v qf[4];
    #pragma unroll
    for (int s = 0; s < 4; ++s) qf[s] = *(const bf16x8v*)(Qp + s * 16);

    f32x16 acc0 = {}, acc1 = {};
    float lsum = 0.f;

    STAGE_TILE(0, (size_t)0);
    __syncthreads();

    int cur = 0;
    for (int t = 0; t < S_LEN / KVB; ++t) {
        const int nxt = cur ^ 1;
        if (t + 1 < S_LEN / KVB) STAGE_TILE(nxt, (size_t)(t + 1) * KVB);
        const char* KsB = (const char*)&Ks[cur][0];
        const char* VsB = (const char*)&Vs[cur][0];
        LDS_SUB_STEP(KsB, VsB, 0);
        LDS_SUB_STEP(KsB, VsB, 32);
        __syncthreads();
        cur = nxt;
    }
#undef STAGE_TILE

    const float linv = 1.f / lsum;
    unsigned short* Orow = O + ((size_t)b * S_LEN + q0 + lo) * DM + h * 64 + hi * 4;
    #pragma unroll
    for (int g = 0; g < 4; ++g) {
        u16x4 st0, st1;
        #pragma unroll
        for (int k2 = 0; k2 < 4; ++k2) {
            st0[k2] = f2bf(acc0[g * 4 + k2] * linv);
            st1[k2] = f2bf(acc1[g * 4 + k2] * linv);
        }
        *(u16x4*)(Orow + g * 8)      = st0;
        *(u16x4*)(Orow + 32 + g * 8) = st1;
    }
}

// ---------------- host launcher ----------------
extern "C" void kernel_launch(void* const* d_in, const int* in_sizes, int n_in,
                              void* d_out, int out_size, void* d_ws, size_t ws_size,
                              hipStream_t stream)
{
    const float* x    = (const float*)d_in[0];
    const float* Wqkv = (const float*)d_in[1];
    const float* bqkv = (const float*)d_in[2];
    const float* Wout = (const float*)d_in[3];
    const float* bout = (const float*)d_in[4];
    float* out = (float*)d_out;

    char* ws = (char*)d_ws;
    // layout (bytes):
    //  [0,         8388608)  xb (x bf16; dead after QKV GEMM)
    //  [8388608,  14680064)  wqkv_t bf16 [3072][1024]
    //  [14680064, 16777216)  wout_t bf16 [1024][1024]
    //  [16777216, 41943040)  qkvb bf16 [4096][3072]  (LIVE through attn: Q,K read from it)
    //  [41943040, 50331648)  attn_o bf16 [4096][1024]
    //  [50331648, 58720256)  vtb bf16 [32][64][2048]
    unsigned short* xb     = (unsigned short*)(ws);
    unsigned short* wqkv_t = (unsigned short*)(ws + 8388608);
    unsigned short* wout_t = (unsigned short*)(ws + 14680064);
    unsigned short* qkvb   = (unsigned short*)(ws + 16777216);
    unsigned short* attn_o = (unsigned short*)(ws + 41943040);
    unsigned short* vtb    = (unsigned short*)(ws + 50331648);

    prep_kernel<<<6144, 256, 0, stream>>>(x, xb, Wqkv, wqkv_t, Wout, wout_t);
    gemm_bt_kernel<0><<<dim3(NQKV / 128, M_ROWS / 128), 256, 0, stream>>>(
        xb, wqkv_t, bqkv, (void*)qkvb, M_ROWS, NQKV, DM);
    split_v_kernel<<<dim3(S_LEN / 64, BATCH * NH), 256, 0, stream>>>(qkvb, vtb);
    attn_kernel<<<512, 256, 0, stream>>>(qkvb, vtb, attn_o);
    gemm_bt_kernel<1><<<dim3(DM / 128, M_ROWS / 128), 256, 0, stream>>>(
        attn_o, wout_t, bout, (void*)out, M_ROWS, DM, DM);
}

// Round 17
// 124.059 us; speedup vs baseline: 1.0203x; 1.0102x over previous
//
#include <hip/hip_runtime.h>
#include <hip/hip_bf16.h>
#include <stdint.h>

// Problem constants
#define S_LEN 2048
#define DM    1024
#define NH    16
#define DKH   64
#define BATCH 2
#define M_ROWS (BATCH * S_LEN)   // 4096
#define NQKV   (3 * DM)          // 3072

typedef short          bf16x8v __attribute__((ext_vector_type(8)));
typedef float          f32x4   __attribute__((ext_vector_type(4)));
typedef float          f32x16  __attribute__((ext_vector_type(16)));
typedef unsigned short u16x4   __attribute__((ext_vector_type(4)));
typedef unsigned short u16x8   __attribute__((ext_vector_type(8)));
typedef unsigned int   u32x2   __attribute__((ext_vector_type(2)));
typedef unsigned int   u32x4   __attribute__((ext_vector_type(4)));

typedef const void __attribute__((address_space(1))) gas_void;
typedef void       __attribute__((address_space(3))) las_void;

static __device__ __forceinline__ unsigned short f2bf(float f) {
    union { float f; uint32_t u; } v; v.f = f;
    uint32_t u = v.u;
    uint32_t r = (u + 0x7fffu + ((u >> 16) & 1u)) >> 16;  // RNE
    return (unsigned short)r;
}

// raw v_exp_f32: D = 2^S0
static __device__ __forceinline__ float exp2_hw(float x) {
    float r;
    asm("v_exp_f32 %0, %1" : "=v"(r) : "v"(x));
    return r;
}

// pack 2 f32 -> 2 bf16 in one u32 (lo = first arg)
static __device__ __forceinline__ uint32_t cvtpk_bf16(float lo, float hi) {
    uint32_t r;
    asm("v_cvt_pk_bf16_f32 %0, %1, %2" : "=v"(r) : "v"(lo), "v"(hi));
    return r;
}
// swap: new_a = {a[0:31], b[0:31]}, new_b = {a[32:63], b[32:63]}
static __device__ __forceinline__ u32x2 pl32swap(uint32_t a, uint32_t b) {
    return __builtin_amdgcn_permlane32_swap(a, b, false, false);
}
static __device__ __forceinline__ float    fbits(uint32_t u) { return __builtin_bit_cast(float, u); }
static __device__ __forceinline__ uint32_t ubits(float f)    { return __builtin_bit_cast(uint32_t, f); }

// ---------------- fused prep: x->bf16 + W transposes (3 kernels in 1) ----------
// blocks [0,2048): cvt x; [2048,5120): transpose Wqkv; [5120,6144): transpose Wout.
__global__ __launch_bounds__(256) void prep_kernel(
    const float* __restrict__ x, unsigned short* __restrict__ xb,
    const float* __restrict__ Wqkv, unsigned short* __restrict__ wqkv_t,
    const float* __restrict__ Wout, unsigned short* __restrict__ wout_t)
{
    const int bid = blockIdx.x;
    const int tid = threadIdx.x;
    __shared__ float t[32][33];

    if (bid < 2048) {
        const int i = bid * 256 + tid;
        f32x4 a = *(const f32x4*)(x + (size_t)i * 8);
        f32x4 b = *(const f32x4*)(x + (size_t)i * 8 + 4);
        u16x8 o;
        #pragma unroll
        for (int j = 0; j < 4; ++j) { o[j] = f2bf(a[j]); o[4 + j] = f2bf(b[j]); }
        *(u16x8*)(xb + (size_t)i * 8) = o;
        return;
    }
    const float* W; unsigned short* Wt; int N, tb;
    if (bid < 2048 + 3072) { W = Wqkv; Wt = wqkv_t; N = NQKV; tb = bid - 2048; }
    else                   { W = Wout; Wt = wout_t; N = DM;   tb = bid - 5120; }
    const int K  = DM;
    const int nb = N / 32;
    const int n0 = (tb % nb) * 32, k0 = (tb / nb) * 32;
    const int tx = tid & 31, ty = tid >> 5;
    #pragma unroll
    for (int i = 0; i < 4; ++i)
        t[ty * 4 + i][tx] = W[(size_t)(k0 + ty * 4 + i) * N + n0 + tx];
    __syncthreads();
    #pragma unroll
    for (int i = 0; i < 4; ++i)
        Wt[(size_t)(n0 + ty * 4 + i) * K + k0 + tx] = f2bf(t[tx][ty * 4 + i]);
}

// ---------------- GEMM (qkv): C[M][N] = A[M][K] * Bt[N][K]^T + bias, bf16 out ----
// (R10-verbatim; 128x128 tile, 3 blocks/CU — m97-structure ceiling, leave alone.)
__global__ __launch_bounds__(256) void gemm_bt_kernel(
    const unsigned short* __restrict__ A, const unsigned short* __restrict__ Bt,
    const float* __restrict__ bias, unsigned short* __restrict__ Cout,
    int M, int N, int K)
{
    __shared__ __attribute__((aligned(16))) unsigned short As[128 * 32];
    __shared__ __attribute__((aligned(16))) unsigned short Bs[128 * 32];

    const int tid  = threadIdx.x;
    const int lane = tid & 63;
    const int w    = tid >> 6;
    const int wr   = w >> 1, wc = w & 1;
    const int lr   = lane & 15, lg = lane >> 4;
    const int m0   = blockIdx.y * 128, n0 = blockIdx.x * 128;

    f32x4 acc[4][4];
    #pragma unroll
    for (int i = 0; i < 4; ++i)
        #pragma unroll
        for (int j = 0; j < 4; ++j) acc[i][j] = (f32x4){0.f, 0.f, 0.f, 0.f};

    for (int kt = 0; kt < K; kt += 32) {
        if (kt) __syncthreads();
        #pragma unroll
        for (int j = 0; j < 2; ++j) {
            const int c  = j * 256 + tid;
            const int r  = c >> 2;
            const int kc = (c & 3) * 8;
            const int cb = j * 256 + (tid & ~63);
            __builtin_amdgcn_global_load_lds(
                (gas_void*)(A + (size_t)(m0 + r) * K + kt + kc),
                (las_void*)((char*)As + (size_t)cb * 16), 16, 0, 0);
            __builtin_amdgcn_global_load_lds(
                (gas_void*)(Bt + (size_t)(n0 + r) * K + kt + kc),
                (las_void*)((char*)Bs + (size_t)cb * 16), 16, 0, 0);
        }
        __syncthreads();

        bf16x8v af[4], bfv[4];
        #pragma unroll
        for (int mi = 0; mi < 4; ++mi)
            af[mi] = *(const bf16x8v*)(&As[(wr * 64 + mi * 16 + lr) * 32 + lg * 8]);
        #pragma unroll
        for (int ni = 0; ni < 4; ++ni)
            bfv[ni] = *(const bf16x8v*)(&Bs[(wc * 64 + ni * 16 + lr) * 32 + lg * 8]);
        #pragma unroll
        for (int mi = 0; mi < 4; ++mi)
            #pragma unroll
            for (int ni = 0; ni < 4; ++ni)
                acc[mi][ni] = __builtin_amdgcn_mfma_f32_16x16x32_bf16(
                    af[mi], bfv[ni], acc[mi][ni], 0, 0, 0);
    }

    const int grow0 = m0 + wr * 64 + lg * 4;
    const int gcol0 = n0 + wc * 64 + lr;
    #pragma unroll
    for (int mi = 0; mi < 4; ++mi)
        #pragma unroll
        for (int ni = 0; ni < 4; ++ni) {
            const int gcol = gcol0 + ni * 16;
            const float bv = bias[gcol];
            #pragma unroll
            for (int r = 0; r < 4; ++r) {
                const size_t idx = (size_t)(grow0 + mi * 16 + r) * N + gcol;
                Cout[idx] = f2bf(acc[mi][ni][r] + bv);
            }
        }
}

// ---------------- GEMM (out): C[4096][1024] f32 = A * Wt^T + bias ----------------
// 64x128 tile -> 512 blocks = 2 blocks/CU (old 128x128 gave 256 = 1/CU, fully
// latency-exposed). Double-buffered staging: stage tile t+1 while computing t,
// ONE barrier per iteration (attn-style; helps precisely when no co-resident
// block can fill the stall). Fragment maps identical to gemm_bt_kernel.
__global__ __launch_bounds__(256) void gemm_out_kernel(
    const unsigned short* __restrict__ A, const unsigned short* __restrict__ Bt,
    const float* __restrict__ bias, float* __restrict__ Cout)
{
    const int M = M_ROWS, N = DM, K = DM;
    __shared__ __attribute__((aligned(16))) unsigned short As[2][64 * 32];
    __shared__ __attribute__((aligned(16))) unsigned short Bs[2][128 * 32];

    const int tid  = threadIdx.x;
    const int lane = tid & 63;
    const int w    = tid >> 6;
    const int wr   = w >> 1, wc = w & 1;          // wave tile: 32 rows x 64 cols
    const int lr   = lane & 15, lg = lane >> 4;
    const int m0   = blockIdx.y * 64, n0 = blockIdx.x * 128;

    f32x4 acc[2][4];
    #pragma unroll
    for (int i = 0; i < 2; ++i)
        #pragma unroll
        for (int j = 0; j < 4; ++j) acc[i][j] = (f32x4){0.f, 0.f, 0.f, 0.f};

    // staging: A tile 64x32 = 256 chunks (1 issue); B tile 128x32 = 512 (2 issues)
    const int sr  = tid >> 2;               // row 0..63
    const int skc = (tid & 3) * 8;          // k elem 0/8/16/24
    const int sdst = (tid & ~63) * 16;      // bytes

#define STAGE_OUT(buf, kt)                                                            \
    do {                                                                              \
        __builtin_amdgcn_global_load_lds(                                             \
            (gas_void*)(A + (size_t)(m0 + sr) * K + (kt) + skc),                      \
            (las_void*)((char*)&As[buf][0] + sdst), 16, 0, 0);                        \
        _Pragma("unroll")                                                             \
        for (int j = 0; j < 2; ++j) {                                                 \
            const int c = j * 256 + tid;                                              \
            const int r = c >> 2;                                                     \
            const int kc2 = (c & 3) * 8;                                              \
            const int cb = j * 256 + (tid & ~63);                                     \
            __builtin_amdgcn_global_load_lds(                                         \
                (gas_void*)(Bt + (size_t)(n0 + r) * K + (kt) + kc2),                  \
                (las_void*)((char*)&Bs[buf][0] + (size_t)cb * 16), 16, 0, 0);         \
        }                                                                             \
    } while (0)

    STAGE_OUT(0, 0);
    __syncthreads();

    int cur = 0;
    for (int kt = 0; kt < K; kt += 32) {
        const int nxt = cur ^ 1;
        if (kt + 32 < K) STAGE_OUT(nxt, kt + 32);

        bf16x8v af[2], bfv[4];
        #pragma unroll
        for (int mi = 0; mi < 2; ++mi)
            af[mi] = *(const bf16x8v*)(&As[cur][(wr * 32 + mi * 16 + lr) * 32 + lg * 8]);
        #pragma unroll
        for (int ni = 0; ni < 4; ++ni)
            bfv[ni] = *(const bf16x8v*)(&Bs[cur][(wc * 64 + ni * 16 + lr) * 32 + lg * 8]);
        #pragma unroll
        for (int mi = 0; mi < 2; ++mi)
            #pragma unroll
            for (int ni = 0; ni < 4; ++ni)
                acc[mi][ni] = __builtin_amdgcn_mfma_f32_16x16x32_bf16(
                    af[mi], bfv[ni], acc[mi][ni], 0, 0, 0);

        __syncthreads();   // staged data landed; all waves done with buf[cur]
        cur = nxt;
    }
#undef STAGE_OUT

    const int grow0 = m0 + wr * 32 + lg * 4;
    const int gcol0 = n0 + wc * 64 + lr;
    #pragma unroll
    for (int mi = 0; mi < 2; ++mi)
        #pragma unroll
        for (int ni = 0; ni < 4; ++ni) {
            const int gcol = gcol0 + ni * 16;
            const float bv = bias[gcol];
            #pragma unroll
            for (int r = 0; r < 4; ++r) {
                const size_t idx = (size_t)(grow0 + mi * 16 + r) * N + gcol;
                Cout[idx] = acc[mi][ni][r] + bv;
            }
        }
}

// ---------------- split V only: qkv V-block -> Vt [bh][64][s] (R10-verbatim) ----
__global__ __launch_bounds__(256) void split_v_kernel(
    const unsigned short* __restrict__ qkv, unsigned short* __restrict__ vt)
{
    const int tid = threadIdx.x;
    const int bh  = blockIdx.y;
    const int h   = bh & 15;
    const int b   = bh >> 4;
    const int s0  = blockIdx.x * 64;
    __shared__ __attribute__((aligned(16))) unsigned short tile[64][68];

    #pragma unroll
    for (int j = 0; j < 4; ++j) {
        const int c  = tid + j * 256;      // 0..1023 (chunks of 4 ushorts)
        const int r  = c >> 4;             // s row 0..63
        const int c4 = (c & 15) * 4;       // dk col 0..60
        const size_t srow = ((size_t)b * S_LEN + s0 + r) * NQKV + 2 * DM + h * 64 + c4;
        *(u16x4*)&tile[r][c4] = *(const u16x4*)(qkv + srow);
    }
    __syncthreads();
    #pragma unroll
    for (int j = 0; j < 4; ++j) {
        const int c   = tid + j * 256;
        const int dkr = c >> 4;            // dk row of Vt
        const int s4  = (c & 15) * 4;      // s col
        u16x4 o;
        #pragma unroll
        for (int i = 0; i < 4; ++i) o[i] = tile[s4 + i][dkr];
        *(u16x4*)(vt + ((size_t)bh * DKH + dkr) * S_LEN + s0 + s4) = o;
    }
}

// ---------------- flash attention: 4-wave block, LDS-staged K/V, static softmax ----
// (R10/R14 kernel, verbatim — best measured config: 58 µs.)
#define EXP_C1 0.18033688f   /* 0.125 * log2(e) : softmax temp in exp2 domain */
#define KVB 64

static __device__ __forceinline__ int swzkey(int r) { return (r ^ (r >> 3)) & 7; }

#define LDS_SUB_STEP(KsB, VsB, ks)                                                   \
do {                                                                                 \
    bf16x8v kc_[4], vc_[4];                                                          \
    _Pragma("unroll")                                                                \
    for (int s_ = 0; s_ < 4; ++s_) {                                                 \
        const int r_ = (ks) + lo;                                                    \
        kc_[s_] = *(const bf16x8v*)((KsB) + r_ * 128 +                               \
                                    (((s_ * 2 + hi) ^ swzkey(r_)) << 4));            \
    }                                                                                \
    _Pragma("unroll")                                                                \
    for (int j_ = 0; j_ < 4; ++j_) {                                                 \
        const int r_ = (j_ >> 1) * 32 + lo;                                          \
        const int cc_ = ((ks) >> 3) + (j_ & 1) * 2 + hi;                             \
        vc_[j_] = *(const bf16x8v*)((VsB) + r_ * 128 +                               \
                                    ((cc_ ^ swzkey(r_)) << 4));                      \
    }                                                                                \
    f32x16 scA = {}, scB = {};                                                       \
    __builtin_amdgcn_s_setprio(1);                                                   \
    scA = __builtin_amdgcn_mfma_f32_32x32x16_bf16(kc_[0], qf[0], scA, 0, 0, 0);      \
    scB = __builtin_amdgcn_mfma_f32_32x32x16_bf16(kc_[1], qf[1], scB, 0, 0, 0);      \
    scA = __builtin_amdgcn_mfma_f32_32x32x16_bf16(kc_[2], qf[2], scA, 0, 0, 0);      \
    scB = __builtin_amdgcn_mfma_f32_32x32x16_bf16(kc_[3], qf[3], scB, 0, 0, 0);      \
    __builtin_amdgcn_s_setprio(0);                                                   \
    f32x16 sc = scA + scB;                                                           \
    float pe_[16];                                                                   \
    _Pragma("unroll")                                                                \
    for (int r_ = 0; r_ < 16; ++r_)                                                  \
        pe_[r_] = exp2_hw(sc[r_] * EXP_C1);                                          \
    float u0_ = (pe_[0] + pe_[1]) + (pe_[2] + pe_[3]);                               \
    float u1_ = (pe_[4] + pe_[5]) + (pe_[6] + pe_[7]);                               \
    float u2_ = (pe_[8] + pe_[9]) + (pe_[10] + pe_[11]);                             \
    float u3_ = (pe_[12] + pe_[13]) + (pe_[14] + pe_[15]);                           \
    float ss_ = (u0_ + u1_) + (u2_ + u3_);                                           \
    { u32x2 sw_ = pl32swap(ubits(ss_), ubits(ss_));                                  \
      ss_ = fbits(sw_[0]) + fbits(sw_[1]); }                                         \
    lsum += ss_;                                                                     \
    uint32_t a01_ = cvtpk_bf16(pe_[0],  pe_[1]),  a23_ = cvtpk_bf16(pe_[2],  pe_[3]);  \
    uint32_t a45_ = cvtpk_bf16(pe_[4],  pe_[5]),  a67_ = cvtpk_bf16(pe_[6],  pe_[7]);  \
    uint32_t b01_ = cvtpk_bf16(pe_[8],  pe_[9]),  b23_ = cvtpk_bf16(pe_[10], pe_[11]); \
    uint32_t b45_ = cvtpk_bf16(pe_[12], pe_[13]), b67_ = cvtpk_bf16(pe_[14], pe_[15]); \
    u32x2 s0_ = pl32swap(a01_, a45_);                                                \
    u32x2 s1_ = pl32swap(a23_, a67_);                                                \
    u32x2 s2_ = pl32swap(b01_, b45_);                                                \
    u32x2 s3_ = pl32swap(b23_, b67_);                                                \
    u32x4 w0_ = { s0_[0], s1_[0], s0_[1], s1_[1] };                                  \
    u32x4 w1_ = { s2_[0], s3_[0], s2_[1], s3_[1] };                                  \
    bf16x8v pa0_ = __builtin_bit_cast(bf16x8v, w0_);                                 \
    bf16x8v pa1_ = __builtin_bit_cast(bf16x8v, w1_);                                 \
    __builtin_amdgcn_s_setprio(1);                                                   \
    acc0 = __builtin_amdgcn_mfma_f32_32x32x16_bf16(vc_[0], pa0_, acc0, 0, 0, 0);     \
    acc0 = __builtin_amdgcn_mfma_f32_32x32x16_bf16(vc_[1], pa1_, acc0, 0, 0, 0);     \
    acc1 = __builtin_amdgcn_mfma_f32_32x32x16_bf16(vc_[2], pa0_, acc1, 0, 0, 0);     \
    acc1 = __builtin_amdgcn_mfma_f32_32x32x16_bf16(vc_[3], pa1_, acc1, 0, 0, 0);     \
    __builtin_amdgcn_s_setprio(0);                                                   \
} while (0)

__global__ __launch_bounds__(256, 2) void attn_kernel(
    const unsigned short* __restrict__ QKV, const unsigned short* __restrict__ Vt,
    unsigned short* __restrict__ O)
{
    const int tid  = threadIdx.x;
    const int w    = tid >> 6;
    const int lane = tid & 63;
    const int lo = lane & 31;
    const int hi = lane >> 5;

    // T1: XCD-chunked bijective swizzle; 512 blocks = 8 XCDs x 64.
    const int flat = blockIdx.x;
    const int virt = (flat & 7) * 64 + (flat >> 3);
    const int bh = virt >> 4;          // 0..31
    const int qb = virt & 15;          // 0..15
    const int b = bh >> 4, h = bh & 15;
    const int q0 = qb * 128 + w * 32;

    __shared__ __attribute__((aligned(16))) unsigned short Ks[2][KVB * 64];
    __shared__ __attribute__((aligned(16))) unsigned short Vs[2][KVB * 64];

    const unsigned short* Kq  = QKV + (size_t)b * S_LEN * NQKV + DM + h * 64;
    const unsigned short* Vtb = Vt + (size_t)bh * DKH * S_LEN;   // [64][2048]

    const int sr  = tid >> 3, scn = tid & 7;
    const size_t kSrc0 = (size_t)sr * NQKV + ((scn ^ swzkey(sr)) * 8);
    const size_t kSrc1 = (size_t)(sr + 32) * NQKV + ((scn ^ swzkey(sr + 32)) * 8);
    const size_t vSrc0 = (size_t)sr * S_LEN + ((scn ^ swzkey(sr)) * 8);
    const size_t vSrc1 = (size_t)(sr + 32) * S_LEN + ((scn ^ swzkey(sr + 32)) * 8);
    const int dstOff0 = (tid & ~63) * 16;
    const int dstOff1 = dstOff0 + 4096;

#define STAGE_TILE(buf, kvOff)                                                        \
    do {                                                                              \
        __builtin_amdgcn_global_load_lds((gas_void*)(Kq + (kvOff) * NQKV + kSrc0),    \
            (las_void*)((char*)&Ks[buf][0] + dstOff0), 16, 0, 0);                     \
        __builtin_amdgcn_global_load_lds((gas_void*)(Kq + (kvOff) * NQKV + kSrc1),    \
            (las_void*)((char*)&Ks[buf][0] + dstOff1), 16, 0, 0);                     \
        __builtin_amdgcn_global_load_lds((gas_void*)(Vtb + (kvOff) + vSrc0),          \
            (las_void*)((char*)&Vs[buf][0] + dstOff0), 16, 0, 0);                     \
        __builtin_amdgcn_global_load_lds((gas_void*)(Vtb + (kvOff) + vSrc1),          \
            (las_void*)((char*)&Vs[buf][0] + dstOff1), 16, 0, 0);                     \
    } while (0)

    const unsigned short* Qp =
        QKV + ((size_t)b * S_LEN + q0 + lo) * NQKV + h * 64 + hi * 8;
    bf16x8v qf[4];
    #pragma unroll
    for (int s = 0; s < 4; ++s) qf[s] = *(const bf16x8v*)(Qp + s * 16);

    f32x16 acc0 = {}, acc1 = {};
    float lsum = 0.f;

    STAGE_TILE(0, (size_t)0);
    __syncthreads();

    int cur = 0;
    for (int t = 0; t < S_LEN / KVB; ++t) {
        const int nxt = cur ^ 1;
        if (t + 1 < S_LEN / KVB) STAGE_TILE(nxt, (size_t)(t + 1) * KVB);
        const char* KsB = (const char*)&Ks[cur][0];
        const char* VsB = (const char*)&Vs[cur][0];
        LDS_SUB_STEP(KsB, VsB, 0);
        LDS_SUB_STEP(KsB, VsB, 32);
        __syncthreads();
        cur = nxt;
    }
#undef STAGE_TILE

    const float linv = 1.f / lsum;
    unsigned short* Orow = O + ((size_t)b * S_LEN + q0 + lo) * DM + h * 64 + hi * 4;
    #pragma unroll
    for (int g = 0; g < 4; ++g) {
        u16x4 st0, st1;
        #pragma unroll
        for (int k2 = 0; k2 < 4; ++k2) {
            st0[k2] = f2bf(acc0[g * 4 + k2] * linv);
            st1[k2] = f2bf(acc1[g * 4 + k2] * linv);
        }
        *(u16x4*)(Orow + g * 8)      = st0;
        *(u16x4*)(Orow + 32 + g * 8) = st1;
    }
}

// ---------------- host launcher ----------------
extern "C" void kernel_launch(void* const* d_in, const int* in_sizes, int n_in,
                              void* d_out, int out_size, void* d_ws, size_t ws_size,
                              hipStream_t stream)
{
    const float* x    = (const float*)d_in[0];
    const float* Wqkv = (const float*)d_in[1];
    const float* bqkv = (const float*)d_in[2];
    const float* Wout = (const float*)d_in[3];
    const float* bout = (const float*)d_in[4];
    float* out = (float*)d_out;

    char* ws = (char*)d_ws;
    // layout (bytes):
    //  [0,         8388608)  xb (x bf16; dead after QKV GEMM)
    //  [8388608,  14680064)  wqkv_t bf16 [3072][1024]
    //  [14680064, 16777216)  wout_t bf16 [1024][1024]
    //  [16777216, 41943040)  qkvb bf16 [4096][3072]  (LIVE through attn: Q,K read from it)
    //  [41943040, 50331648)  attn_o bf16 [4096][1024]
    //  [50331648, 58720256)  vtb bf16 [32][64][2048]
    unsigned short* xb     = (unsigned short*)(ws);
    unsigned short* wqkv_t = (unsigned short*)(ws + 8388608);
    unsigned short* wout_t = (unsigned short*)(ws + 14680064);
    unsigned short* qkvb   = (unsigned short*)(ws + 16777216);
    unsigned short* attn_o = (unsigned short*)(ws + 41943040);
    unsigned short* vtb    = (unsigned short*)(ws + 50331648);

    prep_kernel<<<6144, 256, 0, stream>>>(x, xb, Wqkv, wqkv_t, Wout, wout_t);
    gemm_bt_kernel<<<dim3(NQKV / 128, M_ROWS / 128), 256, 0, stream>>>(
        xb, wqkv_t, bqkv, qkvb, M_ROWS, NQKV, DM);
    split_v_kernel<<<dim3(S_LEN / 64, BATCH * NH), 256, 0, stream>>>(qkvb, vtb);
    attn_kernel<<<512, 256, 0, stream>>>(qkvb, vtb, attn_o);
    gemm_out_kernel<<<dim3(DM / 128, M_ROWS / 64), 256, 0, stream>>>(
        attn_o, wout_t, bout, out);
}